// Round 3
// baseline (360.143 us; speedup 1.0000x reference)
//
#include <hip/hip_runtime.h>
#include <hip/hip_bf16.h>
#include <stdint.h>

#define L_DIM 2048
#define B_DIM 8
#define D_DIM 1024
#define M_DIM (L_DIM * B_DIM)   // 16384 rows
#define N_DIM (3 * D_DIM)       // 3072
#define K_DIM D_DIM             // 1024
#define CH    (B_DIM * D_DIM)   // 8192 scan channels
#define EPSLN 1e-5f
#define NC 128                  // scan chunks (2048 blocks -> 8/CU)
#define CL (L_DIM / NC)         // 16 steps per chunk

typedef __attribute__((ext_vector_type(8))) short short8;
typedef __attribute__((ext_vector_type(4))) float floatx4;

static __device__ __forceinline__ float bf16_lo(unsigned int p) {
    union { unsigned int u; float f; } v; v.u = p << 16; return v.f;
}
static __device__ __forceinline__ float bf16_hi(unsigned int p) {
    union { unsigned int u; float f; } v; v.u = p & 0xffff0000u; return v.f;
}
static __device__ __forceinline__ unsigned short f32_to_bf16(float f) {
    union { float f; unsigned int u; } v;
    v.f = f;
    unsigned int u = v.u;
    u += 0x7fffu + ((u >> 16) & 1u);   // round-to-nearest-even
    return (unsigned short)(u >> 16);
}
static __device__ __forceinline__ float sigmoidf_fast(float v) {
    return 1.0f / (1.0f + __expf(-v));
}
static __device__ __forceinline__ float tanhf_fast(float c) {
    return 1.0f - 2.0f / (1.0f + __expf(2.0f * c));
}

// async global -> LDS, 16B per lane (global_load_lds_dwordx4)
static __device__ __forceinline__ void async16(const void* g, void* l) {
    __builtin_amdgcn_global_load_lds(
        (const __attribute__((address_space(1))) unsigned int*)g,
        (__attribute__((address_space(3))) unsigned int*)l,
        16, 0, 0);
}

// ---------------- LayerNorm: x[M,D] fp32 -> x_norm bf16 [M,D] + mean/rstd ----
__global__ __launch_bounds__(256) void ln_kernel(const float* __restrict__ x,
                                                 const float* __restrict__ gamma,
                                                 const float* __restrict__ beta,
                                                 unsigned short* __restrict__ xn,
                                                 float* __restrict__ meanOut,
                                                 float* __restrict__ rstdOut) {
    const int row = blockIdx.x;
    const int tid = threadIdx.x;
    const float4* xr = (const float4*)(x + (size_t)row * D_DIM);
    float4 v = xr[tid];
    float s  = v.x + v.y + v.z + v.w;
    float s2 = v.x * v.x + v.y * v.y + v.z * v.z + v.w * v.w;
    #pragma unroll
    for (int o = 32; o > 0; o >>= 1) {
        s  += __shfl_xor(s, o, 64);
        s2 += __shfl_xor(s2, o, 64);
    }
    __shared__ float red[8];
    const int wid = tid >> 6;
    if ((tid & 63) == 0) { red[wid] = s; red[4 + wid] = s2; }
    __syncthreads();
    s  = red[0] + red[1] + red[2] + red[3];
    s2 = red[4] + red[5] + red[6] + red[7];
    const float mean = s * (1.0f / D_DIM);
    const float var  = s2 * (1.0f / D_DIM) - mean * mean;
    const float rstd = rsqrtf(var + EPSLN);
    if (tid == 0) { meanOut[row] = mean; rstdOut[row] = rstd; }
    const int col = tid * 4;
    const float4 g = *(const float4*)(gamma + col);
    const float4 b = *(const float4*)(beta + col);
    unsigned short o0 = f32_to_bf16((v.x - mean) * rstd * g.x + b.x);
    unsigned short o1 = f32_to_bf16((v.y - mean) * rstd * g.y + b.y);
    unsigned short o2 = f32_to_bf16((v.z - mean) * rstd * g.z + b.z);
    unsigned short o3 = f32_to_bf16((v.w - mean) * rstd * g.w + b.w);
    uint2 packed;
    packed.x = (unsigned int)o0 | ((unsigned int)o1 << 16);
    packed.y = (unsigned int)o2 | ((unsigned int)o3 << 16);
    *(uint2*)(xn + (size_t)row * D_DIM + col) = packed;
}

// ---------------- W fp32 [3D, D] -> bf16 ----------------
__global__ __launch_bounds__(256) void wconv_kernel(const float* __restrict__ W,
                                                    unsigned short* __restrict__ Wb) {
    const size_t i = ((size_t)blockIdx.x * 256 + threadIdx.x) * 4;
    float4 v = *(const float4*)(W + i);
    uint2 packed;
    packed.x = (unsigned int)f32_to_bf16(v.x) | ((unsigned int)f32_to_bf16(v.y) << 16);
    packed.y = (unsigned int)f32_to_bf16(v.z) | ((unsigned int)f32_to_bf16(v.w) << 16);
    *(uint2*)(Wb + i) = packed;
}

// ---------------- GEMM: ufr[m,e] = sum_k xn[m,k] * W[e,k]  (NT, bf16 MFMA) ---
// 128x128 tile, BK=32, 256 threads = 4 waves, each wave 64x64 (4x4 of 16x16x32).
// LDS k-chunk XOR swizzle: chunk stored at position p has data chunk p^((row>>1)&3)
// (global_load_lds dest is fixed tid*16B, so the swizzle is applied on the
// global source per lane + mirrored on the fragment read). Breaks the 8-way
// bank-quad conflict of the unswizzled row*64B layout down to 2-way (free).
__global__ __launch_bounds__(256) void gemm_kernel(const unsigned short* __restrict__ A,
                                                   const unsigned short* __restrict__ W,
                                                   unsigned short* __restrict__ u,
                                                   unsigned short* __restrict__ f,
                                                   unsigned short* __restrict__ r) {
    __shared__ __align__(16) unsigned short ldsA[128 * 32];
    __shared__ __align__(16) unsigned short ldsB[128 * 32];
    const int tid  = threadIdx.x;
    const int m0   = blockIdx.y * 128;
    const int n0   = blockIdx.x * 128;
    const int wave = tid >> 6;
    const int lane = tid & 63;
    const int quad = lane >> 4;
    const int l16  = lane & 15;
    const int wm   = (wave >> 1) * 64;
    const int wn   = (wave & 1) * 64;

    floatx4 acc[4][4] = {};

    const int rowS   = tid >> 2;                            // staging row 0..63
    const int chunkS = (tid & 3) ^ ((rowS >> 1) & 3);       // swizzled k-chunk
    const int kgS    = chunkS * 8;

    const unsigned short* gA = A + (size_t)(m0 + rowS) * K_DIM + kgS;
    const unsigned short* gB = W + (size_t)(n0 + rowS) * K_DIM + kgS;

    // fragment-read k offset (mirrors the store swizzle; row bits 1..2 == l16 bits 1..2)
    const int ksw = (quad ^ ((l16 >> 1) & 3)) * 8;

    for (int k0 = 0; k0 < K_DIM; k0 += 32) {
        async16(gA + k0,                      &ldsA[(size_t)tid * 8]);
        async16(gA + k0 + (size_t)64 * K_DIM, &ldsA[(size_t)(256 + tid) * 8]);
        async16(gB + k0,                      &ldsB[(size_t)tid * 8]);
        async16(gB + k0 + (size_t)64 * K_DIM, &ldsB[(size_t)(256 + tid) * 8]);
        __syncthreads();   // drains vmcnt(0): LDS tiles complete

        short8 a[4], b[4];
        #pragma unroll
        for (int i = 0; i < 4; i++) {
            a[i] = *(const short8*)&ldsA[(wm + i * 16 + l16) * 32 + ksw];
            b[i] = *(const short8*)&ldsB[(wn + i * 16 + l16) * 32 + ksw];
        }
        #pragma unroll
        for (int i = 0; i < 4; i++)
            #pragma unroll
            for (int j = 0; j < 4; j++)
                acc[i][j] = __builtin_amdgcn_mfma_f32_16x16x32_bf16(a[i], b[j], acc[i][j], 0, 0, 0);
        __syncthreads();   // protect LDS before next stage
    }

    // Epilogue: region uniform per block (N tile of 128 within a 1024 gate span)
    const int region = n0 >> 10;          // 0 -> u, 1 -> f, 2 -> r
    const int nn0 = (n0 & 1023) + wn;
    unsigned short* dst = (region == 0) ? u : ((region == 1) ? f : r);
    const bool sig = (region != 0);
    #pragma unroll
    for (int i = 0; i < 4; i++) {
        #pragma unroll
        for (int j = 0; j < 4; j++) {
            #pragma unroll
            for (int t = 0; t < 4; t++) {
                const int gm = m0 + wm + i * 16 + quad * 4 + t;
                const int nn = nn0 + j * 16 + l16;
                float v = acc[i][j][t];
                if (sig) v = sigmoidf_fast(v);
                dst[(size_t)gm * D_DIM + nn] = f32_to_bf16(v);
            }
        }
    }
}

// ---------------- Scan phase 1: per-chunk affine reduce (2 channels/thread) --
// c_out = A * c_in + b over CL steps;  A = prod f_t,  b = folded offsets
__global__ __launch_bounds__(256) void scan_reduce(const unsigned short* __restrict__ f,
                                                   const unsigned short* __restrict__ u,
                                                   float* __restrict__ Ac,
                                                   float* __restrict__ bc) {
    const int ch2   = (blockIdx.x * 256 + threadIdx.x) * 2;
    const int chunk = blockIdx.y;
    const size_t base = (size_t)chunk * CL * CH + ch2;
    float A0 = 1.0f, b0 = 0.0f, A1 = 1.0f, b1 = 0.0f;
    #pragma unroll 8
    for (int i = 0; i < CL; i++) {
        const size_t idx = base + (size_t)i * CH;
        const unsigned int fp = *(const unsigned int*)(f + idx);
        const unsigned int up = *(const unsigned int*)(u + idx);
        const float f0 = bf16_lo(fp), f1 = bf16_hi(fp);
        const float u0 = bf16_lo(up), u1 = bf16_hi(up);
        b0 = f0 * (b0 - u0) + u0;   // f*b + (1-f)*u
        b1 = f1 * (b1 - u1) + u1;
        A0 *= f0;
        A1 *= f1;
    }
    *(float2*)(Ac + chunk * CH + ch2) = make_float2(A0, A1);
    *(float2*)(bc + chunk * CH + ch2) = make_float2(b0, b1);
}

// ---------------- Scan phase 2: spine (exclusive scan over chunks) -----------
__global__ __launch_bounds__(256) void scan_spine(const float* __restrict__ Ac,
                                                  const float* __restrict__ bc,
                                                  const float* __restrict__ c0,
                                                  float* __restrict__ cst) {
    const int ch = blockIdx.x * 256 + threadIdx.x;
    float c = c0[ch];
    #pragma unroll 4
    for (int j = 0; j < NC; j++) {
        cst[j * CH + ch] = c;
        c = Ac[j * CH + ch] * c + bc[j * CH + ch];
    }
}

// ---------------- Scan phase 3: apply + fused output (2 channels/thread) -----
// out = x + r*tanh(c_t) + (1-r)*x_norm ; x_norm recomputed fp32 from mean/rstd
// (wave-uniform scalar loads) instead of re-reading the 33.5MB bf16 xn array.
__global__ __launch_bounds__(256) void scan_apply(const unsigned short* __restrict__ f,
                                                  const unsigned short* __restrict__ u,
                                                  const unsigned short* __restrict__ r,
                                                  const float* __restrict__ x,
                                                  const float* __restrict__ meanIn,
                                                  const float* __restrict__ rstdIn,
                                                  const float* __restrict__ gamma,
                                                  const float* __restrict__ beta,
                                                  const float* __restrict__ cst,
                                                  float* __restrict__ out,
                                                  float* __restrict__ lastc) {
    const int ch2   = (blockIdx.x * 256 + threadIdx.x) * 2;
    const int chunk = blockIdx.y;
    const int bidx  = ch2 >> 10;       // batch index (uniform per block)
    const int d     = ch2 & 1023;
    const float2 g  = *(const float2*)(gamma + d);
    const float2 be = *(const float2*)(beta + d);
    const size_t base = (size_t)chunk * CL * CH + ch2;
    float2 cc = *(const float2*)(cst + chunk * CH + ch2);
    float c0v = cc.x, c1v = cc.y;
    #pragma unroll 4
    for (int i = 0; i < CL; i++) {
        const int rowLB = (chunk * CL + i) * B_DIM + bidx;   // uniform
        const float mu = meanIn[rowLB];
        const float rs = rstdIn[rowLB];
        const size_t idx = base + (size_t)i * CH;
        const unsigned int fp = *(const unsigned int*)(f + idx);
        const unsigned int up = *(const unsigned int*)(u + idx);
        const unsigned int rp = *(const unsigned int*)(r + idx);
        const float2 xv = *(const float2*)(x + idx);
        const float f0 = bf16_lo(fp), f1 = bf16_hi(fp);
        const float u0 = bf16_lo(up), u1 = bf16_hi(up);
        c0v = f0 * (c0v - u0) + u0;
        c1v = f1 * (c1v - u1) + u1;
        const float r0 = bf16_lo(rp), r1 = bf16_hi(rp);
        const float n0 = (xv.x - mu) * rs * g.x + be.x;
        const float n1 = (xv.y - mu) * rs * g.y + be.y;
        float2 o;
        o.x = xv.x + r0 * tanhf_fast(c0v) + (1.0f - r0) * n0;
        o.y = xv.y + r1 * tanhf_fast(c1v) + (1.0f - r1) * n1;
        *(float2*)(out + idx) = o;
    }
    if (chunk == NC - 1) *(float2*)(lastc + ch2) = make_float2(c0v, c1v);
}

extern "C" void kernel_launch(void* const* d_in, const int* in_sizes, int n_in,
                              void* d_out, int out_size, void* d_ws, size_t ws_size,
                              hipStream_t stream) {
    const float* x     = (const float*)d_in[0];   // (L,B,D)
    const float* c0    = (const float*)d_in[1];   // (B,D)
    const float* W     = (const float*)d_in[2];   // (3D,D)
    const float* gamma = (const float*)d_in[3];   // (D,)
    const float* beta  = (const float*)d_in[4];   // (D,)

    float* out   = (float*)d_out;                       // (L,B,D)
    float* lastc = out + (size_t)M_DIM * D_DIM;         // (B,D)

    char* ws = (char*)d_ws;
    unsigned short* xn = (unsigned short*)ws;  ws += (size_t)M_DIM * K_DIM * 2;  // 33.5 MB
    unsigned short* Wb = (unsigned short*)ws;  ws += (size_t)N_DIM * K_DIM * 2;  // 6.3 MB
    unsigned short* u  = (unsigned short*)ws;  ws += (size_t)M_DIM * D_DIM * 2;  // 33.5 MB
    unsigned short* f  = (unsigned short*)ws;  ws += (size_t)M_DIM * D_DIM * 2;  // 33.5 MB
    unsigned short* r  = (unsigned short*)ws;  ws += (size_t)M_DIM * D_DIM * 2;  // 33.5 MB
    float* meanBuf = (float*)ws;               ws += (size_t)M_DIM * 4;
    float* rstdBuf = (float*)ws;               ws += (size_t)M_DIM * 4;
    float* Ac  = (float*)ws;                   ws += (size_t)NC * CH * 4;
    float* bc  = (float*)ws;                   ws += (size_t)NC * CH * 4;
    float* cst = (float*)ws;                   ws += (size_t)NC * CH * 4;

    ln_kernel<<<M_DIM, 256, 0, stream>>>(x, gamma, beta, xn, meanBuf, rstdBuf);
    wconv_kernel<<<(N_DIM * K_DIM) / 1024, 256, 0, stream>>>(W, Wb);
    gemm_kernel<<<dim3(N_DIM / 128, M_DIM / 128), 256, 0, stream>>>(xn, Wb, u, f, r);
    scan_reduce<<<dim3(CH / 512, NC), 256, 0, stream>>>(f, u, Ac, bc);
    scan_spine<<<CH / 256, 256, 0, stream>>>(Ac, bc, c0, cst);
    scan_apply<<<dim3(CH / 512, NC), 256, 0, stream>>>(f, u, r, x, meanBuf, rstdBuf,
                                                       gamma, beta, cst, out, lastc);
}

// Round 4
// 315.080 us; speedup vs baseline: 1.1430x; 1.1430x over previous
//
#include <hip/hip_runtime.h>
#include <hip/hip_bf16.h>
#include <stdint.h>

#define L_DIM 2048
#define B_DIM 8
#define D_DIM 1024
#define M_DIM (L_DIM * B_DIM)   // 16384 rows
#define N_DIM (3 * D_DIM)       // 3072
#define K_DIM D_DIM             // 1024
#define CH    (B_DIM * D_DIM)   // 8192 scan channels
#define EPSLN 1e-5f
#define NC 128                  // scan chunks (2048 blocks -> 8/CU)
#define CL (L_DIM / NC)         // 16 steps per chunk

typedef __attribute__((ext_vector_type(8))) short short8;
typedef __attribute__((ext_vector_type(4))) float floatx4;

static __device__ __forceinline__ float bf16_lo(unsigned int p) {
    union { unsigned int u; float f; } v; v.u = p << 16; return v.f;
}
static __device__ __forceinline__ float bf16_hi(unsigned int p) {
    union { unsigned int u; float f; } v; v.u = p & 0xffff0000u; return v.f;
}
static __device__ __forceinline__ unsigned short f32_to_bf16(float f) {
    union { float f; unsigned int u; } v;
    v.f = f;
    unsigned int u = v.u;
    u += 0x7fffu + ((u >> 16) & 1u);   // round-to-nearest-even
    return (unsigned short)(u >> 16);
}
static __device__ __forceinline__ float sigmoidf_fast(float v) {
    return 1.0f / (1.0f + __expf(-v));
}
static __device__ __forceinline__ float tanhf_fast(float c) {
    return 1.0f - 2.0f / (1.0f + __expf(2.0f * c));
}

// async global -> LDS, 16B per lane (global_load_lds_dwordx4)
static __device__ __forceinline__ void async16(const void* g, void* l) {
    __builtin_amdgcn_global_load_lds(
        (const __attribute__((address_space(1))) unsigned int*)g,
        (__attribute__((address_space(3))) unsigned int*)l,
        16, 0, 0);
}

// ---------------- LayerNorm: x[M,D] fp32 -> x_norm bf16 [M,D] + mean/rstd ----
__global__ __launch_bounds__(256) void ln_kernel(const float* __restrict__ x,
                                                 const float* __restrict__ gamma,
                                                 const float* __restrict__ beta,
                                                 unsigned short* __restrict__ xn,
                                                 float* __restrict__ meanOut,
                                                 float* __restrict__ rstdOut) {
    const int row = blockIdx.x;
    const int tid = threadIdx.x;
    const float4* xr = (const float4*)(x + (size_t)row * D_DIM);
    float4 v = xr[tid];
    float s  = v.x + v.y + v.z + v.w;
    float s2 = v.x * v.x + v.y * v.y + v.z * v.z + v.w * v.w;
    #pragma unroll
    for (int o = 32; o > 0; o >>= 1) {
        s  += __shfl_xor(s, o, 64);
        s2 += __shfl_xor(s2, o, 64);
    }
    __shared__ float red[8];
    const int wid = tid >> 6;
    if ((tid & 63) == 0) { red[wid] = s; red[4 + wid] = s2; }
    __syncthreads();
    s  = red[0] + red[1] + red[2] + red[3];
    s2 = red[4] + red[5] + red[6] + red[7];
    const float mean = s * (1.0f / D_DIM);
    const float var  = s2 * (1.0f / D_DIM) - mean * mean;
    const float rstd = rsqrtf(var + EPSLN);
    if (tid == 0) { meanOut[row] = mean; rstdOut[row] = rstd; }
    const int col = tid * 4;
    const float4 g = *(const float4*)(gamma + col);
    const float4 b = *(const float4*)(beta + col);
    unsigned short o0 = f32_to_bf16((v.x - mean) * rstd * g.x + b.x);
    unsigned short o1 = f32_to_bf16((v.y - mean) * rstd * g.y + b.y);
    unsigned short o2 = f32_to_bf16((v.z - mean) * rstd * g.z + b.z);
    unsigned short o3 = f32_to_bf16((v.w - mean) * rstd * g.w + b.w);
    uint2 packed;
    packed.x = (unsigned int)o0 | ((unsigned int)o1 << 16);
    packed.y = (unsigned int)o2 | ((unsigned int)o3 << 16);
    *(uint2*)(xn + (size_t)row * D_DIM + col) = packed;
}

// ---------------- W fp32 [3D, D] -> bf16 ----------------
__global__ __launch_bounds__(256) void wconv_kernel(const float* __restrict__ W,
                                                    unsigned short* __restrict__ Wb) {
    const size_t i = ((size_t)blockIdx.x * 256 + threadIdx.x) * 4;
    float4 v = *(const float4*)(W + i);
    uint2 packed;
    packed.x = (unsigned int)f32_to_bf16(v.x) | ((unsigned int)f32_to_bf16(v.y) << 16);
    packed.y = (unsigned int)f32_to_bf16(v.z) | ((unsigned int)f32_to_bf16(v.w) << 16);
    *(uint2*)(Wb + i) = packed;
}

// ---------------- GEMM: ufr[m,e] = sum_k xn[m,k] * W[e,k]  (NT, bf16 MFMA) ---
// 128x128 tile, BK=64 (32KB LDS, still 3 blocks/CU by VGPR), 4 waves, each
// wave 64x64. Each K-iter stages 32KB and runs 32 MFMA/wave (2 k-substeps,
// fragment regs reused) -> barrier drain amortized over 2x the MFMA of BK=32.
// XOR swizzle for 128B-stride rows: store-side data chunk = (tid&7)^((tid>>3)&7)
// (global_load_lds dest is fixed tid*16B), read-side pos = (quad+4s)^(l16&7).
__global__ __launch_bounds__(256) void gemm_kernel(const unsigned short* __restrict__ A,
                                                   const unsigned short* __restrict__ W,
                                                   unsigned short* __restrict__ u,
                                                   unsigned short* __restrict__ f,
                                                   unsigned short* __restrict__ r) {
    __shared__ __align__(16) unsigned short ldsA[128 * 64];
    __shared__ __align__(16) unsigned short ldsB[128 * 64];
    const int tid  = threadIdx.x;
    const int m0   = blockIdx.y * 128;
    const int n0   = blockIdx.x * 128;
    const int wave = tid >> 6;
    const int lane = tid & 63;
    const int quad = lane >> 4;
    const int l16  = lane & 15;
    const int wm   = (wave >> 1) * 64;
    const int wn   = (wave & 1) * 64;

    floatx4 acc[4][4] = {};

    const int rowS   = tid >> 3;                          // staging row 0..31 (pass 0)
    const int chunkS = (tid & 7) ^ (rowS & 7);            // swizzled k-chunk 0..7
    const int kgS    = chunkS * 8;

    const unsigned short* gA = A + (size_t)(m0 + rowS) * K_DIM + kgS;
    const unsigned short* gB = W + (size_t)(n0 + rowS) * K_DIM + kgS;

    // fragment-read position for k-substep s: pos = (quad + 4s) ^ (l16&7)
    const int posX = l16 & 7;

    for (int k0 = 0; k0 < K_DIM; k0 += 64) {
        #pragma unroll
        for (int p = 0; p < 4; p++) {
            async16(gA + k0 + (size_t)(p * 32) * K_DIM, &ldsA[(size_t)(p * 256 + tid) * 8]);
            async16(gB + k0 + (size_t)(p * 32) * K_DIM, &ldsB[(size_t)(p * 256 + tid) * 8]);
        }
        __syncthreads();   // drains vmcnt(0): LDS tiles complete

        #pragma unroll
        for (int s = 0; s < 2; s++) {
            const int pos = (quad + 4 * s) ^ posX;
            short8 a[4], b[4];
            #pragma unroll
            for (int i = 0; i < 4; i++) {
                a[i] = *(const short8*)&ldsA[(wm + i * 16 + l16) * 64 + pos * 8];
                b[i] = *(const short8*)&ldsB[(wn + i * 16 + l16) * 64 + pos * 8];
            }
            #pragma unroll
            for (int i = 0; i < 4; i++)
                #pragma unroll
                for (int j = 0; j < 4; j++)
                    acc[i][j] = __builtin_amdgcn_mfma_f32_16x16x32_bf16(a[i], b[j], acc[i][j], 0, 0, 0);
        }
        __syncthreads();   // protect LDS before next stage
    }

    // Epilogue: region uniform per block (N tile of 128 within a 1024 gate span)
    const int region = n0 >> 10;          // 0 -> u, 1 -> f, 2 -> r
    const int nn0 = (n0 & 1023) + wn;
    unsigned short* dst = (region == 0) ? u : ((region == 1) ? f : r);
    const bool sig = (region != 0);
    #pragma unroll
    for (int i = 0; i < 4; i++) {
        #pragma unroll
        for (int j = 0; j < 4; j++) {
            #pragma unroll
            for (int t = 0; t < 4; t++) {
                const int gm = m0 + wm + i * 16 + quad * 4 + t;
                const int nn = nn0 + j * 16 + l16;
                float v = acc[i][j][t];
                if (sig) v = sigmoidf_fast(v);
                dst[(size_t)gm * D_DIM + nn] = f32_to_bf16(v);
            }
        }
    }
}

// ---------------- Scan phase 1: per-chunk affine reduce (2 channels/thread) --
// c_out = A * c_in + b over CL steps;  A = prod f_t,  b = folded offsets
__global__ __launch_bounds__(256) void scan_reduce(const unsigned short* __restrict__ f,
                                                   const unsigned short* __restrict__ u,
                                                   float* __restrict__ Ac,
                                                   float* __restrict__ bc) {
    const int ch2   = (blockIdx.x * 256 + threadIdx.x) * 2;
    const int chunk = blockIdx.y;
    const size_t base = (size_t)chunk * CL * CH + ch2;
    float A0 = 1.0f, b0 = 0.0f, A1 = 1.0f, b1 = 0.0f;
    #pragma unroll
    for (int i = 0; i < CL; i++) {
        const size_t idx = base + (size_t)i * CH;
        const unsigned int fp = *(const unsigned int*)(f + idx);
        const unsigned int up = *(const unsigned int*)(u + idx);
        const float f0 = bf16_lo(fp), f1 = bf16_hi(fp);
        const float u0 = bf16_lo(up), u1 = bf16_hi(up);
        b0 = f0 * (b0 - u0) + u0;   // f*b + (1-f)*u
        b1 = f1 * (b1 - u1) + u1;
        A0 *= f0;
        A1 *= f1;
    }
    *(float2*)(Ac + chunk * CH + ch2) = make_float2(A0, A1);
    *(float2*)(bc + chunk * CH + ch2) = make_float2(b0, b1);
}

// ---------------- Scan phase 2: spine (exclusive scan over chunks) -----------
// unroll 16: compiler batches 16 independent (A,b) loads ahead of the FMA chain
__global__ __launch_bounds__(256) void scan_spine(const float* __restrict__ Ac,
                                                  const float* __restrict__ bc,
                                                  const float* __restrict__ c0,
                                                  float* __restrict__ cst) {
    const int ch = blockIdx.x * 256 + threadIdx.x;
    float c = c0[ch];
    #pragma unroll 16
    for (int j = 0; j < NC; j++) {
        cst[j * CH + ch] = c;
        c = Ac[j * CH + ch] * c + bc[j * CH + ch];
    }
}

// ---------------- Scan phase 3: apply + fused output (2 channels/thread) -----
// out = x + r*tanh(c_t) + (1-r)*x_norm ; x_norm recomputed fp32 from mean/rstd
__global__ __launch_bounds__(256) void scan_apply(const unsigned short* __restrict__ f,
                                                  const unsigned short* __restrict__ u,
                                                  const unsigned short* __restrict__ r,
                                                  const float* __restrict__ x,
                                                  const float* __restrict__ meanIn,
                                                  const float* __restrict__ rstdIn,
                                                  const float* __restrict__ gamma,
                                                  const float* __restrict__ beta,
                                                  const float* __restrict__ cst,
                                                  float* __restrict__ out,
                                                  float* __restrict__ lastc) {
    const int ch2   = (blockIdx.x * 256 + threadIdx.x) * 2;
    const int chunk = blockIdx.y;
    const int bidx  = ch2 >> 10;       // batch index (uniform per block)
    const int d     = ch2 & 1023;
    const float2 g  = *(const float2*)(gamma + d);
    const float2 be = *(const float2*)(beta + d);
    const size_t base = (size_t)chunk * CL * CH + ch2;
    float2 cc = *(const float2*)(cst + chunk * CH + ch2);
    float c0v = cc.x, c1v = cc.y;
    #pragma unroll 4
    for (int i = 0; i < CL; i++) {
        const int rowLB = (chunk * CL + i) * B_DIM + bidx;   // uniform
        const float mu = meanIn[rowLB];
        const float rs = rstdIn[rowLB];
        const size_t idx = base + (size_t)i * CH;
        const unsigned int fp = *(const unsigned int*)(f + idx);
        const unsigned int up = *(const unsigned int*)(u + idx);
        const unsigned int rp = *(const unsigned int*)(r + idx);
        const float2 xv = *(const float2*)(x + idx);
        const float f0 = bf16_lo(fp), f1 = bf16_hi(fp);
        const float u0 = bf16_lo(up), u1 = bf16_hi(up);
        c0v = f0 * (c0v - u0) + u0;
        c1v = f1 * (c1v - u1) + u1;
        const float r0 = bf16_lo(rp), r1 = bf16_hi(rp);
        const float n0 = (xv.x - mu) * rs * g.x + be.x;
        const float n1 = (xv.y - mu) * rs * g.y + be.y;
        float2 o;
        o.x = xv.x + r0 * tanhf_fast(c0v) + (1.0f - r0) * n0;
        o.y = xv.y + r1 * tanhf_fast(c1v) + (1.0f - r1) * n1;
        *(float2*)(out + idx) = o;
    }
    if (chunk == NC - 1) *(float2*)(lastc + ch2) = make_float2(c0v, c1v);
}

extern "C" void kernel_launch(void* const* d_in, const int* in_sizes, int n_in,
                              void* d_out, int out_size, void* d_ws, size_t ws_size,
                              hipStream_t stream) {
    const float* x     = (const float*)d_in[0];   // (L,B,D)
    const float* c0    = (const float*)d_in[1];   // (B,D)
    const float* W     = (const float*)d_in[2];   // (3D,D)
    const float* gamma = (const float*)d_in[3];   // (D,)
    const float* beta  = (const float*)d_in[4];   // (D,)

    float* out   = (float*)d_out;                       // (L,B,D)
    float* lastc = out + (size_t)M_DIM * D_DIM;         // (B,D)

    char* ws = (char*)d_ws;
    unsigned short* xn = (unsigned short*)ws;  ws += (size_t)M_DIM * K_DIM * 2;  // 33.5 MB
    unsigned short* Wb = (unsigned short*)ws;  ws += (size_t)N_DIM * K_DIM * 2;  // 6.3 MB
    unsigned short* u  = (unsigned short*)ws;  ws += (size_t)M_DIM * D_DIM * 2;  // 33.5 MB
    unsigned short* f  = (unsigned short*)ws;  ws += (size_t)M_DIM * D_DIM * 2;  // 33.5 MB
    unsigned short* r  = (unsigned short*)ws;  ws += (size_t)M_DIM * D_DIM * 2;  // 33.5 MB
    float* meanBuf = (float*)ws;               ws += (size_t)M_DIM * 4;
    float* rstdBuf = (float*)ws;               ws += (size_t)M_DIM * 4;
    float* Ac  = (float*)ws;                   ws += (size_t)NC * CH * 4;
    float* bc  = (float*)ws;                   ws += (size_t)NC * CH * 4;
    float* cst = (float*)ws;                   ws += (size_t)NC * CH * 4;

    ln_kernel<<<M_DIM, 256, 0, stream>>>(x, gamma, beta, xn, meanBuf, rstdBuf);
    wconv_kernel<<<(N_DIM * K_DIM) / 1024, 256, 0, stream>>>(W, Wb);
    gemm_kernel<<<dim3(N_DIM / 128, M_DIM / 128), 256, 0, stream>>>(xn, Wb, u, f, r);
    scan_reduce<<<dim3(CH / 512, NC), 256, 0, stream>>>(f, u, Ac, bc);
    scan_spine<<<CH / 256, 256, 0, stream>>>(Ac, bc, c0, cst);
    scan_apply<<<dim3(CH / 512, NC), 256, 0, stream>>>(f, u, r, x, meanBuf, rstdBuf,
                                                       gamma, beta, cst, out, lastc);
}